// Round 2
// baseline (2744.517 us; speedup 1.0000x reference)
//
#include <hip/hip_runtime.h>
#include <hip/hip_bf16.h>
#include <stdint.h>

#define NSTEP 126
#define NEVAL 504
#define POISON 0xAAAAAAAAu

typedef __bf16 v8bf __attribute__((ext_vector_type(8)));
typedef float  v4f  __attribute__((ext_vector_type(4)));

__device__ __forceinline__ unsigned short f2bf(float x) {
  union { float f; uint32_t u; } v; v.f = x;
  uint32_t u = v.u;
  uint32_t r = (u + 0x7FFFu + ((u >> 16) & 1u)) >> 16;
  return (unsigned short)r;
}
__device__ __forceinline__ float bf2f(unsigned short b) {
  union { uint32_t u; float f; } v; v.u = ((uint32_t)b) << 16;
  return v.f;
}
// packed RNE f32->bf16x2 (same rounding as f2bf; HW-validated in round 1)
__device__ __forceinline__ uint32_t cvt_pk_bf16(float lo, float hi) {
  uint32_t r;
  asm("v_cvt_pk_bf16_f32 %0, %1, %2" : "=v"(r) : "v"(lo), "v"(hi));
  return r;
}

// raw barrier: LDS-visibility only (lgkmcnt), does NOT drain vmcnt —
// global prefetches/stores stay in flight across it (m201-verified pattern).
#define BARL() asm volatile("s_waitcnt lgkmcnt(0)\n\ts_barrier" ::: "memory")

// ---------------- dtype detection ----------------
__global__ void k_detect(const uint32_t* __restrict__ xw, int* flag) {
  __shared__ int cnt;
  if (threadIdx.x == 0) cnt = 0;
  __syncthreads();
  uint32_t w = xw[threadIdx.x];
  int e = (int)((w >> 7) & 0xFF);
  int good = ((e >= 100) && (e <= 144)) || ((w & 0xFFFFu) == 0u);
  atomicAdd(&cnt, good);
  __syncthreads();
  if (threadIdx.x == 0) *flag = (cnt >= 192) ? 1 : 0;
}

// ---------------- input conversion ----------------
#define NCVT 15
struct CvtArgs {
  const void* src[NCVT];
  int dstoff[NCVT];
  int len[NCVT];
  int kind[NCVT];   // 1 = transpose initial_w; 2 = conv2 weight relayout
  int total;
};
__global__ void k_convert(CvtArgs a, float* __restrict__ ws, const int* __restrict__ flag) {
  int f = *flag;
  for (int i = blockIdx.x*256 + threadIdx.x; i < a.total; i += gridDim.x*256) {
    int t = 0; int rem = i;
    while (rem >= a.len[t]) { rem -= a.len[t]; t++; }
    float v = f ? bf2f(((const unsigned short*)a.src[t])[rem])
                : ((const float*)a.src[t])[rem];
    int d;
    if (a.kind[t] == 1) { int h = rem >> 9, c = rem & 511; d = a.dstoff[t] + c*64 + h; }
    else if (a.kind[t] == 2) {
      int co = rem / 288, r2 = rem % 288;
      int ci = r2 / 9, tt = r2 % 9;
      d = a.dstoff[t] + (co >> 4)*4608 + (ci*16 + (co & 15))*9 + tt;
    }
    else d = a.dstoff[t] + rem;
    ws[d] = v;
  }
}

__global__ void k_wbf16(const void* __restrict__ w2src, const void* __restrict__ w1src,
                        unsigned short* __restrict__ w2bf, unsigned short* __restrict__ w1bf,
                        const int* __restrict__ flag) {
  int f = *flag;
  const long N2 = 4194304, N1 = 8192;
  for (long i = (long)blockIdx.x*256 + threadIdx.x; i < N2 + N1; i += (long)gridDim.x*256) {
    if (i < N2) w2bf[i] = f ? ((const unsigned short*)w2src)[i] : f2bf(((const float*)w2src)[i]);
    else { long j = i - N2; w1bf[j] = f ? ((const unsigned short*)w1src)[j] : f2bf(((const float*)w1src)[j]); }
  }
}

// ---------------- conv1 5x5 pad2, 1->32, relu ----------------
__global__ void k_conv1(const float* __restrict__ xf, const float* __restrict__ w,
                        const float* __restrict__ bias, float* __restrict__ h1) {
  int x = threadIdx.x;        // 0..127
  int y = blockIdx.x;         // 0..31
  int b = blockIdx.y;         // 0..63
  const float* xin = xf + (long)b*4096;
  float in[25];
  #pragma unroll
  for (int ky = 0; ky < 5; ky++) {
    int yy = y + ky - 2;
    #pragma unroll
    for (int kx = 0; kx < 5; kx++) {
      int xx = x + kx - 2;
      in[ky*5+kx] = (yy >= 0 && yy < 32 && xx >= 0 && xx < 128) ? xin[yy*128 + xx] : 0.f;
    }
  }
  for (int co = 0; co < 32; co++) {
    float acc = bias[co];
    #pragma unroll
    for (int t = 0; t < 25; t++) acc += in[t] * w[co*25 + t];
    h1[(((long)b*32 + co)*32 + y)*128 + x] = fmaxf(acc, 0.f);
  }
}

// ---------------- conv2 3x3 pad1, 32->32, relu ----------------
#define LD2 132
__global__ __launch_bounds__(256) void k_conv2(const float* __restrict__ h1, const float* __restrict__ w,
                                               const float* __restrict__ bias, float* __restrict__ h2) {
  __shared__ float s[32][3][LD2];
  int y = blockIdx.x, b = blockIdx.y;
  int tid = threadIdx.x;
  for (int i = tid; i < 32*3*LD2; i += 256) {
    int ci = i / (3*LD2);
    int r  = (i / LD2) % 3;
    int xx = i % LD2;
    int yy = y + r - 1, sx = xx - 1;
    float v = 0.f;
    if (yy >= 0 && yy < 32 && sx >= 0 && sx < 128) v = h1[(((long)b*32+ci)*32+yy)*128+sx];
    s[ci][r][xx] = v;
  }
  __syncthreads();
  int x = tid & 127;
  int half = __builtin_amdgcn_readfirstlane(tid >> 7);
  const float* wb = w + half*4608;          // [ci][co16][9] contiguous
  float acc[16];
  #pragma unroll
  for (int i = 0; i < 16; i++) acc[i] = bias[half*16 + i];
  #pragma unroll 2
  for (int ci = 0; ci < 32; ci++) {
    float xv[9];
    #pragma unroll
    for (int r = 0; r < 3; r++)
      #pragma unroll
      for (int k = 0; k < 3; k++) xv[r*3+k] = s[ci][r][x + k];
    #pragma unroll
    for (int co = 0; co < 16; co++) {
      const float* wr = wb + (ci*16 + co)*9;
      #pragma unroll
      for (int t = 0; t < 9; t++) acc[co] += xv[t] * wr[t];
    }
  }
  #pragma unroll
  for (int co = 0; co < 16; co++)
    h2[(((long)b*32 + half*16 + co)*32 + y)*128 + x] = fmaxf(acc[co], 0.f);
}

// ---------------- maxpool 2x2 + channel mean ----------------
__global__ void k_pool(const float* __restrict__ h2, float* __restrict__ pooled, float* __restrict__ attm) {
  int bc = blockIdx.x;                 // b*32+c
  const float* src = h2 + (long)bc*4096;
  float* dst = pooled + (long)bc*1024;
  float sum = 0.f;
  for (int i = threadIdx.x; i < 1024; i += 256) {
    int py = i >> 6, px = i & 63;
    const float* p = src + py*256 + px*2;
    float m = fmaxf(fmaxf(p[0], p[1]), fmaxf(p[128], p[129]));
    dst[i] = m;
    sum += m;
  }
  __shared__ float red[256];
  red[threadIdx.x] = sum;
  __syncthreads();
  for (int s2 = 128; s2 > 0; s2 >>= 1) {
    if (threadIdx.x < s2) red[threadIdx.x] += red[threadIdx.x + s2];
    __syncthreads();
  }
  if (threadIdx.x == 0) attm[bc] = red[0] * (1.f/1024.f);
}

// ---------------- attention MLP ----------------
__global__ void k_att(const float* __restrict__ attm, const float* __restrict__ w1, const float* __restrict__ b1,
                      const float* __restrict__ w2, const float* __restrict__ b2, float* __restrict__ atts) {
  int b = threadIdx.x;
  if (b < 64) {
    float hb[4];
    #pragma unroll
    for (int j = 0; j < 4; j++) {
      float s = b1[j];
      for (int i = 0; i < 32; i++) s += attm[b*32+i]*w1[j*32+i];
      hb[j] = fmaxf(s, 0.f);
    }
    for (int o = 0; o < 32; o++) {
      float s = b2[o];
      #pragma unroll
      for (int j = 0; j < 4; j++) s += hb[j]*w2[o*4+j];
      atts[b*32+o] = 1.f/(1.f + __expf(-s));
    }
  }
}

// ---------------- scale + transpose to seq[b][t][f], f=c*16+hh ----------------
__global__ void k_seq(const float* __restrict__ pooled, const float* __restrict__ atts, float* __restrict__ seq) {
  for (int idx = blockIdx.x*256 + threadIdx.x; idx < 64*64*512; idx += gridDim.x*256) {
    int b = idx >> 15;
    int t = (idx >> 9) & 63;
    int fch = idx & 511;
    int c = fch >> 4, hh = fch & 15;
    seq[idx] = pooled[(((long)b*32 + c)*16 + hh)*64 + t] * atts[b*32 + c];
  }
}

// ---------------- natural cubic spline coeffs + dXdt table (fused) ----------------
__global__ __launch_bounds__(256, 1) void k_spline(const float* __restrict__ seq,
                                                   float* __restrict__ dxt) {
  int id = blockIdx.x*256 + threadIdx.x;     // 0..32767
  int b = id >> 9, f = id & 511;
  const float* xp = seq + (long)b*32768 + f;
  float xv[64];
  #pragma unroll
  for (int t = 0; t < 64; t++) xv[t] = xp[t*512];
  float cp[62], dp[62];
  float pc = 0.f, pd = 0.f;
  #pragma unroll
  for (int i = 0; i < 62; i++) {
    float rhs = 6.f*(xv[i+2] - 2.f*xv[i+1] + xv[i]);
    float inv = 1.f/(4.f - pc);
    pc = inv;
    pd = (rhs - pd)*inv;
    cp[i] = pc; dp[i] = pd;
  }
  #pragma unroll
  for (int i = 60; i >= 0; i--) dp[i] = dp[i] - cp[i]*dp[i+1];
  const float i6 = 1.f/6.f;
  float* op = dxt + (long)b*512 + f;
  #pragma unroll
  for (int t = 0; t < 63; t++) {
    float M0 = (t == 0)  ? 0.f : dp[t-1];
    float M1 = (t == 62) ? 0.f : dp[t];
    float sb = (xv[t+1] - xv[t]) - (2.f*M0 + M1)*i6;
    float sc = 0.5f*M0;
    float sd = (M1 - M0)*i6;
    float* o = op + (long)(4*t)*32768;
    o[0]      = sb;                                  // fr = 0
    o[32768]  = sb + 0.5f*sc + 0.1875f*sd;           // fr = 0.25
    o[65536]  = sb + sc + 0.75f*sd;                  // fr = 0.5
    o[98304]  = sb + 1.5f*sc + 1.6875f*sd;           // fr = 0.75
    if (t == 62) o[131072] = sb + 2.f*sc + 3.f*sd;   // m = 252, fr = 1
  }
}

// ---------------- z0 = seq[:,0,:] @ initial_w^T + b ----------------
__global__ void k_z0(const float* __restrict__ seq, const float* __restrict__ iwT,
                     const float* __restrict__ ib, float* __restrict__ z0) {
  __shared__ float s0[512];
  int b = blockIdx.x, h = threadIdx.x;
  for (int c = h; c < 512; c += 64) s0[c] = seq[(long)b*32768 + c];
  __syncthreads();
  float acc = ib[h];
  for (int c = 0; c < 512; c++) acc += s0[c]*iwT[c*64 + h];
  z0[b*64 + h] = acc;
}

// ---------------- persistent RK4 CDE integrator ----------------
// v8: 2-chain interleave. 128 blocks = 64 hb x 2; each block serves two
// independent b-quarter chains {bqp, bqp+2} with SHARED register-resident
// W2/W1 weights (hb-dependent only). Stages alternate A(e),B(e): chain X's
// agent-store visibility + consumer-load RT age out under chain Y's stage.
// kv and dxt loads for a chain are ISSUED during the partner's stage and
// consumed one stage later (poison-fallback reload covers producer lag).
// All __syncthreads() in the loop replaced by lgkmcnt-only raw barriers so
// in-flight global prefetches/k-stores are NOT drained at barriers.
// Exchange protocol (poison data-is-the-flag, per-word verify) unchanged.
#define DXSZ (16*524 + 1024)
__global__ __launch_bounds__(512, 2) void k_ode(
    const float* __restrict__ z0buf,
    const unsigned short* __restrict__ w2bf,   // [32768][128]
    const unsigned short* __restrict__ w1bf,   // [128][64]
    const float* __restrict__ f1bias,
    const float* __restrict__ f2bias,
    const float* __restrict__ dxt,             // [253][64][512]
    const float* __restrict__ outw,
    const float* __restrict__ outb,
    uint32_t* kpart,                           // [504][4 cq][64 hb][16 b] (poisoned)
    void* dout,
    const int* __restrict__ flag)
{
  __shared__ __align__(16) unsigned short zs[16*72];   // z bf16 [16 b][64 h] pad (shared A/B)
  __shared__ __align__(16) unsigned short ub[16*136];  // u bf16 [16 b][128 u] pad (shared A/B)
  __shared__ __align__(16) float dxsA[DXSZ];           // dx fp32 chain A (+pad: CU exclusivity)
  __shared__ __align__(16) float dxsB[DXSZ];           // dx fp32 chain B
  __shared__ float kred[128];                          // [16 b][8 wv]

  int tid = threadIdx.x;
  int bl  = blockIdx.x;          // 0..127
  int hb  = bl >> 1;             // 0..63 — this block's h (all 512 c)
  int bqp = bl & 1;
  int cqA = bqp,     B0A = bqp*16;        // chain A: b-quarter bqp
  int cqB = bqp + 2, B0B = bqp*16 + 32;   // chain B: b-quarter bqp+2
  int lane = tid & 63, wv = tid >> 6;     // 8 waves
  int q = lane >> 4, ln = lane & 15;

  // ---- persistent fragments (hb-dependent: SHARED by both chains) ----
  v8bf w2f[4][4];
  #pragma unroll
  for (int jt = 0; jt < 4; jt++)
    #pragma unroll
    for (int ks = 0; ks < 4; ks++) {
      long row = (long)hb*512 + wv*64 + jt*16 + ln;
      w2f[jt][ks] = *(const v8bf*)(w2bf + row*128 + ks*32 + q*8);
    }
  v8bf w1f[2];                  // u-rows wv*16..+16
  #pragma unroll
  for (int ks = 0; ks < 2; ks++)
    w1f[ks] = *(const v8bf*)(w1bf + (wv*16 + ln)*64 + ks*32 + q*8);
  float fb2[4][4];
  #pragma unroll
  for (int jt = 0; jt < 4; jt++)
    #pragma unroll
    for (int r = 0; r < 4; r++)
      fb2[jt][r] = f2bias[(long)hb*512 + wv*64 + jt*16 + q*4 + r];
  float fb1[4];
  #pragma unroll
  for (int r = 0; r < 4; r++)
    fb1[r] = f1bias[wv*16 + q*4 + r];

  // z state: thread owns b-local = tid&15, h-pair = (tid>>4)*2, per chain
  int zbL = tid & 15;
  int hg  = tid >> 4;           // 0..31
  int h0  = hg*2;               // 0..62
  float zA[2], zaA[2], zB[2], zaB[2];
  #pragma unroll
  for (int i = 0; i < 2; i++) {
    zA[i] = z0buf[(B0A+zbL)*64 + h0 + i]; zaA[i] = 0.f;
    zB[i] = z0buf[(B0B+zbL)*64 + h0 + i]; zaB[i] = 0.f;
  }

  uint32_t kvA[2], kvB[2];
  float4 dxrA[4], dxrB[4];
  // prologue: issue dx(m=0) for both chains
  #pragma unroll
  for (int i = 0; i < 4; i++) {
    int fi = i*512 + tid;            // 2048 float4 = [16 b][128 f4]
    int bb = fi >> 7, c4 = fi & 127;
    dxrA[i] = *(const float4*)(dxt + (B0A+bb)*512 + c4*4);
    dxrB[i] = *(const float4*)(dxt + (B0B+bb)*512 + c4*4);
  }

  const float dt6 = 0.5f/6.f;

  // One RK4 sub-stage for chain (cq,B0). Also issues the PARTNER chain's
  // next kv loads (eIs,cqIs -> kvIs) and this chain's next dx loads.
  auto STAGE = [&](int e, int cq, int B0,
                   float (&z)[2], float (&za)[2], uint32_t (&kv)[2],
                   float4 (&dxr)[4], float (&dxs)[DXSZ],
                   int eIs, int cqIs, uint32_t (&kvIs)[2], bool isValid) {
    int st = e & 3;
    bool dodx = (e & 1) || (e == 0);
    // issue partner kv prefetch FIRST (max aging before its consume)
    if (isValid) {
      const uint32_t* kp2 = kpart + ((long)eIs*4 + cqIs)*1024;
      kvIs[0] = __hip_atomic_load(kp2 + (h0+0)*16 + zbL, __ATOMIC_RELAXED, __HIP_MEMORY_SCOPE_AGENT);
      kvIs[1] = __hip_atomic_load(kp2 + (h0+1)*16 + zbL, __ATOMIC_RELAXED, __HIP_MEMORY_SCOPE_AGENT);
    }
    // consume own kv (prefetched during partner's previous stage)
    if (e > 0) {
      const uint32_t* kp = kpart + ((long)(e-1)*4 + cq)*1024;
      float kvf[2];
      #pragma unroll
      for (int i = 0; i < 2; i++) {
        uint32_t v = kv[i];
        const uint32_t* p = kp + (h0+i)*16 + zbL;
        while (v == POISON) {
          __builtin_amdgcn_s_sleep(1);
          v = __hip_atomic_load(p, __ATOMIC_RELAXED, __HIP_MEMORY_SCOPE_AGENT);
        }
        kvf[i] = __uint_as_float(v);
      }
      if (st == 0) {
        z[0] += dt6*(za[0] + kvf[0]);
        z[1] += dt6*(za[1] + kvf[1]);
        za[0] = 0.f; za[1] = 0.f;
        *(uint32_t*)(zs + zbL*72 + h0) = cvt_pk_bf16(z[0], z[1]);
      } else {
        float wk = (st == 1) ? 1.f : 2.f;
        float aa = (st == 3) ? 0.5f : 0.25f;
        za[0] += wk*kvf[0];
        za[1] += wk*kvf[1];
        *(uint32_t*)(zs + zbL*72 + h0) = cvt_pk_bf16(z[0] + aa*kvf[0], z[1] + aa*kvf[1]);
      }
    } else {
      *(uint32_t*)(zs + zbL*72 + h0) = cvt_pk_bf16(z[0], z[1]);
    }
    // dx stage write (regs loaded one stage ago)
    if (dodx) {
      #pragma unroll
      for (int i = 0; i < 4; i++) {
        int fi = i*512 + tid;
        int bb = fi >> 7, c4 = fi & 127;
        *(float4*)(dxs + bb*524 + c4*4) = dxr[i];
      }
    }
    // issue own dx loads for eval e+1 (only changes entering odd evals)
    if (!(e & 1)) {
      int mn = ((e+1) >> 2)*2 + ((((e+1) & 3) + 1) >> 1);
      #pragma unroll
      for (int i = 0; i < 4; i++) {
        int fi = i*512 + tid;
        int bb = fi >> 7, c4 = fi & 127;
        dxr[i] = *(const float4*)(dxt + (long)mn*32768 + (B0+bb)*512 + c4*4);
      }
    }
    BARL();
    // W1: wave computes u rows wv*16..+16 for the 16 b (bias in C-in)
    v8bf zf[2];
    #pragma unroll
    for (int ks = 0; ks < 2; ks++)
      zf[ks] = *(const v8bf*)(zs + ln*72 + ks*32 + q*8);
    {
      v4f ua = (v4f){fb1[0], fb1[1], fb1[2], fb1[3]};
      #pragma unroll
      for (int ks = 0; ks < 2; ks++)
        ua = __builtin_amdgcn_mfma_f32_16x16x32_bf16(w1f[ks], zf[ks], ua, 0, 0, 0);
      uint2 upk;
      upk.x = cvt_pk_bf16(fmaxf(ua[0], 0.f), fmaxf(ua[1], 0.f));
      upk.y = cvt_pk_bf16(fmaxf(ua[2], 0.f), fmaxf(ua[3], 0.f));
      *(uint2*)(ub + ln*136 + wv*16 + q*4) = upk;
    }
    BARL();
    // W2 (wave's 64 c-rows, all 16 b) + tanh + dot dx -> per-wave partial
    v8bf uf[4];
    #pragma unroll
    for (int ks = 0; ks < 4; ks++)
      uf[ks] = *(const v8bf*)(ub + ln*136 + ks*32 + q*8);
    float ksum = 0.f;
    #pragma unroll
    for (int jt = 0; jt < 4; jt++) {
      v4f acc = (v4f){fb2[jt][0], fb2[jt][1], fb2[jt][2], fb2[jt][3]};
      #pragma unroll
      for (int ks = 0; ks < 4; ks++)
        acc = __builtin_amdgcn_mfma_f32_16x16x32_bf16(w2f[jt][ks], uf[ks], acc, 0, 0, 0);
      v4f dx4 = *(const v4f*)(dxs + ln*524 + wv*64 + jt*16 + q*4);
      #pragma unroll
      for (int r = 0; r < 4; r++) {
        float xv2 = acc[r];
        float ex = __expf(2.f*xv2);
        float th = 1.f - 2.f*__builtin_amdgcn_rcpf(ex + 1.f);
        ksum += th*dx4[r];
      }
    }
    ksum += __shfl_xor(ksum, 16, 64);
    ksum += __shfl_xor(ksum, 32, 64);
    if (lane < 16)
      kred[ln*8 + wv] = ksum;
    BARL();
    // wave0: combine 8 wave-partials -> FINAL k, one 64B line store.
    // The store is the readiness signal (nudge poison collision).
    if (tid < 16) {
      const float* kr = kred + tid*8;
      float v = ((((((kr[0]+kr[1])+kr[2])+kr[3])+kr[4])+kr[5])+kr[6])+kr[7];
      uint32_t uv = __float_as_uint(v);
      if (uv == POISON) uv ^= 1u;
      __hip_atomic_store(kpart + (((long)e*4 + cq)*64 + hb)*16 + tid, uv,
                         __ATOMIC_RELAXED, __HIP_MEMORY_SCOPE_AGENT);
    }
    // no trailing barrier: next stage's BAR covers all WAR hazards (audited)
  };

  #pragma unroll 1
  for (int e = 0; e < NEVAL; e++) {
    // A(e): issues kvB for B(e) (consumes k_B(e-1), stored last stage)
    STAGE(e, cqA, B0A, zA, zaA, kvA, dxrA, dxsA, e-1, cqB, kvB, (e >= 1));
    // B(e): issues kvA for A(e+1) (consumes k_A(e), stored this stage-pair);
    // at e=503 this prefetches chain A's final kv for the epilogue.
    STAGE(e, cqB, B0B, zB, zaB, kvB, dxrB, dxsB, e,   cqA, kvA, true);
  }

  // final: only output blocks (hb==0 -> bl<2) need the last k
  if (hb == 0) {
    {  // finish chain A (kvA prefetched during B(503))
      const uint32_t* kp = kpart + ((long)(NEVAL-1)*4 + cqA)*1024;
      #pragma unroll
      for (int i = 0; i < 2; i++) {
        uint32_t v = kvA[i];
        const uint32_t* p = kp + (h0+i)*16 + zbL;
        while (v == POISON) {
          __builtin_amdgcn_s_sleep(1);
          v = __hip_atomic_load(p, __ATOMIC_RELAXED, __HIP_MEMORY_SCOPE_AGENT);
        }
        zA[i] += dt6*(zaA[i] + __uint_as_float(v));
      }
    }
    {  // finish chain B
      const uint32_t* kp = kpart + ((long)(NEVAL-1)*4 + cqB)*1024;
      #pragma unroll
      for (int i = 0; i < 2; i++) {
        const uint32_t* p = kp + (h0+i)*16 + zbL;
        uint32_t v = __hip_atomic_load(p, __ATOMIC_RELAXED, __HIP_MEMORY_SCOPE_AGENT);
        while (v == POISON) {
          __builtin_amdgcn_s_sleep(1);
          v = __hip_atomic_load(p, __ATOMIC_RELAXED, __HIP_MEMORY_SCOPE_AGENT);
        }
        zB[i] += dt6*(zaB[i] + __uint_as_float(v));
      }
    }
    int fl = *flag;
    {  // chain A output
      float o0 = zA[0]*outw[h0] + zA[1]*outw[h0+1];
      float o1 = zA[0]*outw[64+h0] + zA[1]*outw[64+h0+1];
      BARL();
      dxsA[hg*32 + zbL*2 + 0] = o0;    // po[32 grp][16 b][2]
      dxsA[hg*32 + zbL*2 + 1] = o1;
      BARL();
      if (tid < 32) {
        int bloc = tid >> 1, comp = tid & 1;
        float s = outb[comp];
        #pragma unroll
        for (int g = 0; g < 32; g++) s += dxsA[g*32 + bloc*2 + comp];
        int b = B0A + bloc;
        if (fl) ((unsigned short*)dout)[b*2 + comp] = f2bf(s);
        else    ((float*)dout)[b*2 + comp] = s;
      }
      BARL();
    }
    {  // chain B output
      float o0 = zB[0]*outw[h0] + zB[1]*outw[h0+1];
      float o1 = zB[0]*outw[64+h0] + zB[1]*outw[64+h0+1];
      dxsA[hg*32 + zbL*2 + 0] = o0;
      dxsA[hg*32 + zbL*2 + 1] = o1;
      BARL();
      if (tid < 32) {
        int bloc = tid >> 1, comp = tid & 1;
        float s = outb[comp];
        #pragma unroll
        for (int g = 0; g < 32; g++) s += dxsA[g*32 + bloc*2 + comp];
        int b = B0B + bloc;
        if (fl) ((unsigned short*)dout)[b*2 + comp] = f2bf(s);
        else    ((float*)dout)[b*2 + comp] = s;
      }
    }
  }
}

// ---------------- host ----------------
extern "C" void kernel_launch(void* const* d_in, const int* in_sizes, int n_in,
                              void* d_out, int out_size, void* d_ws, size_t ws_size,
                              hipStream_t stream) {
  (void)in_sizes; (void)n_in; (void)out_size; (void)ws_size;
  float* ws = (float*)d_ws;
  size_t o = 0;
  auto alloc = [&](size_t n) { size_t r = o; o += (n + 63) & ~(size_t)63; return r; };
  size_t o_flag = alloc(64);
  size_t o_xf   = alloc(262144);
  size_t o_c1w  = alloc(800);
  size_t o_c1b  = alloc(32);
  size_t o_c2w  = alloc(9216);
  size_t o_c2b  = alloc(32);
  size_t o_a1w  = alloc(128);
  size_t o_a1b  = alloc(4);
  size_t o_a2w  = alloc(128);
  size_t o_a2b  = alloc(32);
  size_t o_iwT  = alloc(32768);
  size_t o_ib   = alloc(64);
  size_t o_f1b  = alloc(128);
  size_t o_f2b  = alloc(32768);
  size_t o_ow   = alloc(128);
  size_t o_ob   = alloc(2);
  size_t o_z0   = alloc(4096);
  size_t o_attm = alloc(2048);
  size_t o_atts = alloc(2048);
  size_t o_w1bf = alloc(4096);      // ushort[8192]
  size_t o_w2bf = alloc(2097152);   // ushort[4194304]
  size_t o_h1   = alloc(8388608);   // conv1 out; later pooled+seq
  size_t o_h2   = alloc(8388608);   // conv2 out; later dxt (253*32768 floats)
  size_t o_kpart= alloc(4128768);   // k data [504][4][64][16] — fresh, harness-poisoned
  size_t o_pool = o_h1;
  size_t o_seq  = o_h1 + 2097152;
  size_t o_dxt  = o_h2;

  int* flag = (int*)(ws + o_flag);

  hipLaunchKernelGGL(k_detect, dim3(1), dim3(256), 0, stream, (const uint32_t*)d_in[0], flag);

  CvtArgs ca;
  const int  si[NCVT]  = {0,1,2,3,4,5,6,7,8,9,10,12,14,15,16};
  const size_t dofs[NCVT] = {o_xf,o_c1w,o_c1b,o_c2w,o_c2b,o_a1w,o_a1b,o_a2w,o_a2b,o_iwT,o_ib,o_f1b,o_f2b,o_ow,o_ob};
  const int  ln[NCVT]  = {262144,800,32,9216,32,128,4,128,32,32768,64,128,32768,128,2};
  int tot = 0;
  for (int i = 0; i < NCVT; i++) {
    ca.src[i] = d_in[si[i]];
    ca.dstoff[i] = (int)dofs[i];
    ca.len[i] = ln[i];
    ca.kind[i] = (si[i] == 9) ? 1 : ((si[i] == 3) ? 2 : 0);
    tot += ln[i];
  }
  ca.total = tot;
  hipLaunchKernelGGL(k_convert, dim3(512), dim3(256), 0, stream, ca, ws, flag);
  hipLaunchKernelGGL(k_wbf16, dim3(2048), dim3(256), 0, stream, d_in[13], d_in[11],
                     (unsigned short*)(ws + o_w2bf), (unsigned short*)(ws + o_w1bf), flag);
  hipLaunchKernelGGL(k_conv1, dim3(32,64), dim3(128), 0, stream, ws+o_xf, ws+o_c1w, ws+o_c1b, ws+o_h1);
  hipLaunchKernelGGL(k_conv2, dim3(32,64), dim3(256), 0, stream, ws+o_h1, ws+o_c2w, ws+o_c2b, ws+o_h2);
  hipLaunchKernelGGL(k_pool, dim3(2048), dim3(256), 0, stream, ws+o_h2, ws+o_pool, ws+o_attm);
  hipLaunchKernelGGL(k_att, dim3(1), dim3(64), 0, stream, ws+o_attm, ws+o_a1w, ws+o_a1b, ws+o_a2w, ws+o_a2b, ws+o_atts);
  hipLaunchKernelGGL(k_seq, dim3(2048), dim3(256), 0, stream, ws+o_pool, ws+o_atts, ws+o_seq);
  hipLaunchKernelGGL(k_spline, dim3(128), dim3(256), 0, stream, ws+o_seq, ws+o_dxt);
  hipLaunchKernelGGL(k_z0, dim3(64), dim3(64), 0, stream, ws+o_seq, ws+o_iwT, ws+o_ib, ws+o_z0);

  hipLaunchKernelGGL(k_ode, dim3(128), dim3(512), 0, stream,
                     ws + o_z0,
                     (const unsigned short*)(ws + o_w2bf),
                     (const unsigned short*)(ws + o_w1bf),
                     ws + o_f1b, ws + o_f2b,
                     ws + o_dxt, ws + o_ow, ws + o_ob,
                     (uint32_t*)(ws + o_kpart),
                     d_out, (const int*)flag);
}

// Round 3
// 1518.085 us; speedup vs baseline: 1.8079x; 1.8079x over previous
//
#include <hip/hip_runtime.h>
#include <hip/hip_bf16.h>
#include <stdint.h>

#define NSTEP 126
#define NEVAL 504
#define POISON 0xAAAAAAAAu

typedef __bf16 v8bf __attribute__((ext_vector_type(8)));
typedef float  v4f  __attribute__((ext_vector_type(4)));

__device__ __forceinline__ unsigned short f2bf(float x) {
  union { float f; uint32_t u; } v; v.f = x;
  uint32_t u = v.u;
  uint32_t r = (u + 0x7FFFu + ((u >> 16) & 1u)) >> 16;
  return (unsigned short)r;
}
__device__ __forceinline__ float bf2f(unsigned short b) {
  union { uint32_t u; float f; } v; v.u = ((uint32_t)b) << 16;
  return v.f;
}
// packed RNE f32->bf16x2 (same rounding as f2bf; HW-validated rounds 1-2)
__device__ __forceinline__ uint32_t cvt_pk_bf16(float lo, float hi) {
  uint32_t r;
  asm("v_cvt_pk_bf16_f32 %0, %1, %2" : "=v"(r) : "v"(lo), "v"(hi));
  return r;
}

// raw barrier: LDS-visibility only (lgkmcnt), does NOT drain vmcnt —
// the k-store and global prefetches stay in flight across it
// (correctness validated in the v8 run; removes the ~600cy store-retire
// drain v6 paid at the poll barrier).
#define BARL() asm volatile("s_waitcnt lgkmcnt(0)\n\ts_barrier" ::: "memory")

// ---------------- dtype detection ----------------
__global__ void k_detect(const uint32_t* __restrict__ xw, int* flag) {
  __shared__ int cnt;
  if (threadIdx.x == 0) cnt = 0;
  __syncthreads();
  uint32_t w = xw[threadIdx.x];
  int e = (int)((w >> 7) & 0xFF);
  int good = ((e >= 100) && (e <= 144)) || ((w & 0xFFFFu) == 0u);
  atomicAdd(&cnt, good);
  __syncthreads();
  if (threadIdx.x == 0) *flag = (cnt >= 192) ? 1 : 0;
}

// ---------------- input conversion ----------------
#define NCVT 15
struct CvtArgs {
  const void* src[NCVT];
  int dstoff[NCVT];
  int len[NCVT];
  int kind[NCVT];   // 1 = transpose initial_w; 2 = conv2 weight relayout
  int total;
};
__global__ void k_convert(CvtArgs a, float* __restrict__ ws, const int* __restrict__ flag) {
  int f = *flag;
  for (int i = blockIdx.x*256 + threadIdx.x; i < a.total; i += gridDim.x*256) {
    int t = 0; int rem = i;
    while (rem >= a.len[t]) { rem -= a.len[t]; t++; }
    float v = f ? bf2f(((const unsigned short*)a.src[t])[rem])
                : ((const float*)a.src[t])[rem];
    int d;
    if (a.kind[t] == 1) { int h = rem >> 9, c = rem & 511; d = a.dstoff[t] + c*64 + h; }
    else if (a.kind[t] == 2) {
      int co = rem / 288, r2 = rem % 288;
      int ci = r2 / 9, tt = r2 % 9;
      d = a.dstoff[t] + (co >> 4)*4608 + (ci*16 + (co & 15))*9 + tt;
    }
    else d = a.dstoff[t] + rem;
    ws[d] = v;
  }
}

__global__ void k_wbf16(const void* __restrict__ w2src, const void* __restrict__ w1src,
                        unsigned short* __restrict__ w2bf, unsigned short* __restrict__ w1bf,
                        const int* __restrict__ flag) {
  int f = *flag;
  const long N2 = 4194304, N1 = 8192;
  for (long i = (long)blockIdx.x*256 + threadIdx.x; i < N2 + N1; i += (long)gridDim.x*256) {
    if (i < N2) w2bf[i] = f ? ((const unsigned short*)w2src)[i] : f2bf(((const float*)w2src)[i]);
    else { long j = i - N2; w1bf[j] = f ? ((const unsigned short*)w1src)[j] : f2bf(((const float*)w1src)[j]); }
  }
}

// ---------------- conv1 5x5 pad2, 1->32, relu ----------------
__global__ void k_conv1(const float* __restrict__ xf, const float* __restrict__ w,
                        const float* __restrict__ bias, float* __restrict__ h1) {
  int x = threadIdx.x;        // 0..127
  int y = blockIdx.x;         // 0..31
  int b = blockIdx.y;         // 0..63
  const float* xin = xf + (long)b*4096;
  float in[25];
  #pragma unroll
  for (int ky = 0; ky < 5; ky++) {
    int yy = y + ky - 2;
    #pragma unroll
    for (int kx = 0; kx < 5; kx++) {
      int xx = x + kx - 2;
      in[ky*5+kx] = (yy >= 0 && yy < 32 && xx >= 0 && xx < 128) ? xin[yy*128 + xx] : 0.f;
    }
  }
  for (int co = 0; co < 32; co++) {
    float acc = bias[co];
    #pragma unroll
    for (int t = 0; t < 25; t++) acc += in[t] * w[co*25 + t];
    h1[(((long)b*32 + co)*32 + y)*128 + x] = fmaxf(acc, 0.f);
  }
}

// ---------------- conv2 3x3 pad1, 32->32, relu ----------------
#define LD2 132
__global__ __launch_bounds__(256) void k_conv2(const float* __restrict__ h1, const float* __restrict__ w,
                                               const float* __restrict__ bias, float* __restrict__ h2) {
  __shared__ float s[32][3][LD2];
  int y = blockIdx.x, b = blockIdx.y;
  int tid = threadIdx.x;
  for (int i = tid; i < 32*3*LD2; i += 256) {
    int ci = i / (3*LD2);
    int r  = (i / LD2) % 3;
    int xx = i % LD2;
    int yy = y + r - 1, sx = xx - 1;
    float v = 0.f;
    if (yy >= 0 && yy < 32 && sx >= 0 && sx < 128) v = h1[(((long)b*32+ci)*32+yy)*128+sx];
    s[ci][r][xx] = v;
  }
  __syncthreads();
  int x = tid & 127;
  int half = __builtin_amdgcn_readfirstlane(tid >> 7);
  const float* wb = w + half*4608;          // [ci][co16][9] contiguous
  float acc[16];
  #pragma unroll
  for (int i = 0; i < 16; i++) acc[i] = bias[half*16 + i];
  #pragma unroll 2
  for (int ci = 0; ci < 32; ci++) {
    float xv[9];
    #pragma unroll
    for (int r = 0; r < 3; r++)
      #pragma unroll
      for (int k = 0; k < 3; k++) xv[r*3+k] = s[ci][r][x + k];
    #pragma unroll
    for (int co = 0; co < 16; co++) {
      const float* wr = wb + (ci*16 + co)*9;
      #pragma unroll
      for (int t = 0; t < 9; t++) acc[co] += xv[t] * wr[t];
    }
  }
  #pragma unroll
  for (int co = 0; co < 16; co++)
    h2[(((long)b*32 + half*16 + co)*32 + y)*128 + x] = fmaxf(acc[co], 0.f);
}

// ---------------- maxpool 2x2 + channel mean ----------------
__global__ void k_pool(const float* __restrict__ h2, float* __restrict__ pooled, float* __restrict__ attm) {
  int bc = blockIdx.x;                 // b*32+c
  const float* src = h2 + (long)bc*4096;
  float* dst = pooled + (long)bc*1024;
  float sum = 0.f;
  for (int i = threadIdx.x; i < 1024; i += 256) {
    int py = i >> 6, px = i & 63;
    const float* p = src + py*256 + px*2;
    float m = fmaxf(fmaxf(p[0], p[1]), fmaxf(p[128], p[129]));
    dst[i] = m;
    sum += m;
  }
  __shared__ float red[256];
  red[threadIdx.x] = sum;
  __syncthreads();
  for (int s2 = 128; s2 > 0; s2 >>= 1) {
    if (threadIdx.x < s2) red[threadIdx.x] += red[threadIdx.x + s2];
    __syncthreads();
  }
  if (threadIdx.x == 0) attm[bc] = red[0] * (1.f/1024.f);
}

// ---------------- attention MLP ----------------
__global__ void k_att(const float* __restrict__ attm, const float* __restrict__ w1, const float* __restrict__ b1,
                      const float* __restrict__ w2, const float* __restrict__ b2, float* __restrict__ atts) {
  int b = threadIdx.x;
  if (b < 64) {
    float hb[4];
    #pragma unroll
    for (int j = 0; j < 4; j++) {
      float s = b1[j];
      for (int i = 0; i < 32; i++) s += attm[b*32+i]*w1[j*32+i];
      hb[j] = fmaxf(s, 0.f);
    }
    for (int o = 0; o < 32; o++) {
      float s = b2[o];
      #pragma unroll
      for (int j = 0; j < 4; j++) s += hb[j]*w2[o*4+j];
      atts[b*32+o] = 1.f/(1.f + __expf(-s));
    }
  }
}

// ---------------- scale + transpose to seq[b][t][f], f=c*16+hh ----------------
__global__ void k_seq(const float* __restrict__ pooled, const float* __restrict__ atts, float* __restrict__ seq) {
  for (int idx = blockIdx.x*256 + threadIdx.x; idx < 64*64*512; idx += gridDim.x*256) {
    int b = idx >> 15;
    int t = (idx >> 9) & 63;
    int fch = idx & 511;
    int c = fch >> 4, hh = fch & 15;
    seq[idx] = pooled[(((long)b*32 + c)*16 + hh)*64 + t] * atts[b*32 + c];
  }
}

// ---------------- natural cubic spline coeffs + dXdt table (fused) ----------------
__global__ __launch_bounds__(256, 1) void k_spline(const float* __restrict__ seq,
                                                   float* __restrict__ dxt) {
  int id = blockIdx.x*256 + threadIdx.x;     // 0..32767
  int b = id >> 9, f = id & 511;
  const float* xp = seq + (long)b*32768 + f;
  float xv[64];
  #pragma unroll
  for (int t = 0; t < 64; t++) xv[t] = xp[t*512];
  float cp[62], dp[62];
  float pc = 0.f, pd = 0.f;
  #pragma unroll
  for (int i = 0; i < 62; i++) {
    float rhs = 6.f*(xv[i+2] - 2.f*xv[i+1] + xv[i]);
    float inv = 1.f/(4.f - pc);
    pc = inv;
    pd = (rhs - pd)*inv;
    cp[i] = pc; dp[i] = pd;
  }
  #pragma unroll
  for (int i = 60; i >= 0; i--) dp[i] = dp[i] - cp[i]*dp[i+1];
  const float i6 = 1.f/6.f;
  float* op = dxt + (long)b*512 + f;
  #pragma unroll
  for (int t = 0; t < 63; t++) {
    float M0 = (t == 0)  ? 0.f : dp[t-1];
    float M1 = (t == 62) ? 0.f : dp[t];
    float sb = (xv[t+1] - xv[t]) - (2.f*M0 + M1)*i6;
    float sc = 0.5f*M0;
    float sd = (M1 - M0)*i6;
    float* o = op + (long)(4*t)*32768;
    o[0]      = sb;                                  // fr = 0
    o[32768]  = sb + 0.5f*sc + 0.1875f*sd;           // fr = 0.25
    o[65536]  = sb + sc + 0.75f*sd;                  // fr = 0.5
    o[98304]  = sb + 1.5f*sc + 1.6875f*sd;           // fr = 0.75
    if (t == 62) o[131072] = sb + 2.f*sc + 3.f*sd;   // m = 252, fr = 1
  }
}

// ---------------- z0 = seq[:,0,:] @ initial_w^T + b ----------------
__global__ void k_z0(const float* __restrict__ seq, const float* __restrict__ iwT,
                     const float* __restrict__ ib, float* __restrict__ z0) {
  __shared__ float s0[512];
  int b = blockIdx.x, h = threadIdx.x;
  for (int c = h; c < 512; c += 64) s0[c] = seq[(long)b*32768 + c];
  __syncthreads();
  float acc = ib[h];
  for (int c = 0; c < 512; c++) acc += s0[c]*iwT[c*64 + h];
  z0[b*64 + h] = acc;
}

// ---------------- persistent RK4 CDE integrator ----------------
// v9 = v6 exchange protocol (proven best: wave-1 word0 poll + barrier +
// per-thread kv agent loads w/ rare poison fallback) + the independently
// proven VALU wins from v7 (cvt_pk packing, bias in MFMA C-in, transposed
// kred for b128 combine) + lgkmcnt-only barriers in the loop so the k-store
// and dxt prefetches are NOT drained at barriers (validated in v8 run).
// Grid back to 256 blocks (64 hb x 4 bq), single dxs, CU-exclusive LDS.
__global__ __launch_bounds__(512, 2) void k_ode(
    const float* __restrict__ z0buf,
    const unsigned short* __restrict__ w2bf,   // [32768][128]
    const unsigned short* __restrict__ w1bf,   // [128][64]
    const float* __restrict__ f1bias,
    const float* __restrict__ f2bias,
    const float* __restrict__ dxt,             // [253][64][512]
    const float* __restrict__ outw,
    const float* __restrict__ outb,
    uint32_t* kpart,                           // [504][4 bq][64 hb][16 b] (poisoned)
    void* dout,
    const int* __restrict__ flag)
{
  __shared__ __align__(16) unsigned short zs[16*72];       // z bf16 [16 b][64 h] pad
  __shared__ __align__(16) unsigned short ub[16*136];      // u bf16 [16 b][128 u] pad
  __shared__ __align__(16) float dxs[16*524 + 10560];      // dx fp32 + CU-exclusivity pad
  __shared__ float kred[128];                              // [16 b][8 wv]

  int tid = threadIdx.x;
  int bl  = blockIdx.x;
  int hb  = bl >> 2;            // 0..63 — this block's h (all 512 c)
  int bq  = bl & 3;             // b-quarter
  int B0  = bq*16;
  int lane = tid & 63, wv = tid >> 6;   // 8 waves
  int q = lane >> 4, ln = lane & 15;

  // ---- persistent fragments: wave wv owns c-rows wv*64..+64 ----
  v8bf w2f[4][4];
  #pragma unroll
  for (int jt = 0; jt < 4; jt++)
    #pragma unroll
    for (int ks = 0; ks < 4; ks++) {
      long row = (long)hb*512 + wv*64 + jt*16 + ln;
      w2f[jt][ks] = *(const v8bf*)(w2bf + row*128 + ks*32 + q*8);
    }
  v8bf w1f[2];                  // u-rows wv*16..+16
  #pragma unroll
  for (int ks = 0; ks < 2; ks++)
    w1f[ks] = *(const v8bf*)(w1bf + (wv*16 + ln)*64 + ks*32 + q*8);
  float fb2[4][4];
  #pragma unroll
  for (int jt = 0; jt < 4; jt++)
    #pragma unroll
    for (int r = 0; r < 4; r++)
      fb2[jt][r] = f2bias[(long)hb*512 + wv*64 + jt*16 + q*4 + r];
  float fb1[4];
  #pragma unroll
  for (int r = 0; r < 4; r++)
    fb1[r] = f1bias[wv*16 + q*4 + r];

  // z state: thread owns b-local = tid&15, h-pair = (tid>>4)*2
  int zbL = tid & 15;
  int hg  = tid >> 4;           // 0..31
  int h0  = hg*2;               // 0..62
  float z[2], zacc[2];
  #pragma unroll
  for (int i = 0; i < 2; i++) { z[i] = z0buf[(B0+zbL)*64 + h0 + i]; zacc[i] = 0.f; }

  const float dt6 = 0.5f/6.f;
  int e = 0;
  for (int step = 0; step < NSTEP; step++) {
    #pragma unroll 1
    for (int stage = 0; stage < 4; stage++, e++) {
      bool do_dx = (stage == 1) || (stage == 3) || (e == 0);
      int m = 2*step + ((stage + 1) >> 1);
      float4 dxr[4];
      if (do_dx) {
        #pragma unroll
        for (int i = 0; i < 4; i++) {
          int fi = i*512 + tid;          // 2048 float4 = [16 b][128 f4]
          int bb = fi >> 7, c4 = fi & 127;
          dxr[i] = *(const float4*)(dxt + (long)m*32768 + (B0+bb)*512 + c4*4);
        }
      }
      if (e > 0) {
        const uint32_t* kp = kpart + ((long)(e-1)*4 + bq)*1024;
        // wave-1: poll one word per 64B k-line (v6 protocol — word0 only)
        if (tid >= 64 && tid < 128) {
          const uint32_t* pp = kp + (tid - 64)*16;
          while (__hip_atomic_load(pp, __ATOMIC_RELAXED, __HIP_MEMORY_SCOPE_AGENT) == POISON)
            __builtin_amdgcn_s_sleep(1);
        }
        BARL();
        // kv loads (data aged in by poll+barrier); rare poison fallback
        uint32_t kvu[2];
        const uint32_t* p0 = kp + (h0+0)*16 + zbL;
        const uint32_t* p1 = kp + (h0+1)*16 + zbL;
        kvu[0] = __hip_atomic_load(p0, __ATOMIC_RELAXED, __HIP_MEMORY_SCOPE_AGENT);
        kvu[1] = __hip_atomic_load(p1, __ATOMIC_RELAXED, __HIP_MEMORY_SCOPE_AGENT);
        // dxs LDS writes overlap the kv load latency
        if (do_dx) {
          #pragma unroll
          for (int i = 0; i < 4; i++) {
            int fi = i*512 + tid;
            int bb = fi >> 7, c4 = fi & 127;
            *(float4*)(dxs + bb*524 + c4*4) = dxr[i];
          }
        }
        while (kvu[0] == POISON) {
          __builtin_amdgcn_s_sleep(1);
          kvu[0] = __hip_atomic_load(p0, __ATOMIC_RELAXED, __HIP_MEMORY_SCOPE_AGENT);
        }
        while (kvu[1] == POISON) {
          __builtin_amdgcn_s_sleep(1);
          kvu[1] = __hip_atomic_load(p1, __ATOMIC_RELAXED, __HIP_MEMORY_SCOPE_AGENT);
        }
        float kv0 = __uint_as_float(kvu[0]);
        float kv1 = __uint_as_float(kvu[1]);
        if (stage == 0) {
          z[0] += dt6*(zacc[0] + kv0);
          z[1] += dt6*(zacc[1] + kv1);
          zacc[0] = 0.f; zacc[1] = 0.f;
          *(uint32_t*)(zs + zbL*72 + h0) = cvt_pk_bf16(z[0], z[1]);
        } else {
          float wk = (stage == 1) ? 1.f : 2.f;
          float aa = (stage == 3) ? 0.5f : 0.25f;
          zacc[0] += wk*kv0;
          zacc[1] += wk*kv1;
          *(uint32_t*)(zs + zbL*72 + h0) = cvt_pk_bf16(z[0] + aa*kv0, z[1] + aa*kv1);
        }
      } else {
        *(uint32_t*)(zs + zbL*72 + h0) = cvt_pk_bf16(z[0], z[1]);
        if (do_dx) {
          #pragma unroll
          for (int i = 0; i < 4; i++) {
            int fi = i*512 + tid;
            int bb = fi >> 7, c4 = fi & 127;
            *(float4*)(dxs + bb*524 + c4*4) = dxr[i];
          }
        }
      }
      BARL();
      // W1: wave computes u rows wv*16..+16 for the 16 b (bias in C-in)
      v8bf zf[2];
      #pragma unroll
      for (int ks = 0; ks < 2; ks++)
        zf[ks] = *(const v8bf*)(zs + ln*72 + ks*32 + q*8);
      {
        v4f ua = (v4f){fb1[0], fb1[1], fb1[2], fb1[3]};
        #pragma unroll
        for (int ks = 0; ks < 2; ks++)
          ua = __builtin_amdgcn_mfma_f32_16x16x32_bf16(w1f[ks], zf[ks], ua, 0, 0, 0);
        uint2 upk;
        upk.x = cvt_pk_bf16(fmaxf(ua[0], 0.f), fmaxf(ua[1], 0.f));
        upk.y = cvt_pk_bf16(fmaxf(ua[2], 0.f), fmaxf(ua[3], 0.f));
        *(uint2*)(ub + ln*136 + wv*16 + q*4) = upk;
      }
      BARL();
      // W2 (wave's 64 c-rows, all 16 b) + tanh + dot dx -> per-wave partial
      v8bf uf[4];
      #pragma unroll
      for (int ks = 0; ks < 4; ks++)
        uf[ks] = *(const v8bf*)(ub + ln*136 + ks*32 + q*8);
      float ksum = 0.f;
      #pragma unroll
      for (int jt = 0; jt < 4; jt++) {
        v4f acc = (v4f){fb2[jt][0], fb2[jt][1], fb2[jt][2], fb2[jt][3]};
        #pragma unroll
        for (int ks = 0; ks < 4; ks++)
          acc = __builtin_amdgcn_mfma_f32_16x16x32_bf16(w2f[jt][ks], uf[ks], acc, 0, 0, 0);
        v4f dx4 = *(const v4f*)(dxs + ln*524 + wv*64 + jt*16 + q*4);
        #pragma unroll
        for (int r = 0; r < 4; r++) {
          float xv2 = acc[r];
          float ex = __expf(2.f*xv2);
          float th = 1.f - 2.f*__builtin_amdgcn_rcpf(ex + 1.f);
          ksum += th*dx4[r];
        }
      }
      ksum += __shfl_xor(ksum, 16, 64);
      ksum += __shfl_xor(ksum, 32, 64);
      if (lane < 16)
        kred[ln*8 + wv] = ksum;
      BARL();
      // wave0: combine 8 wave-partials (contiguous b128 reads) -> FINAL k,
      // one 64B line store. The store itself is the readiness signal.
      if (tid < 16) {
        const float* kr = kred + tid*8;
        float v = ((((((kr[0]+kr[1])+kr[2])+kr[3])+kr[4])+kr[5])+kr[6])+kr[7];
        uint32_t uv = __float_as_uint(v);
        if (uv == POISON) uv ^= 1u;
        __hip_atomic_store(kpart + (((long)e*4 + bq)*64 + hb)*16 + tid, uv,
                           __ATOMIC_RELAXED, __HIP_MEMORY_SCOPE_AGENT);
      }
      // no trailing barrier: next eval's poll barrier covers all WAR hazards
    }
  }
  // final: only output blocks (hb==0 -> bl<4) need the last k
  if (hb == 0) {
    const uint32_t* kp = kpart + ((long)(NEVAL-1)*4 + bq)*1024;
    if (tid >= 64 && tid < 128) {
      const uint32_t* pp = kp + (tid - 64)*16;
      while (__hip_atomic_load(pp, __ATOMIC_RELAXED, __HIP_MEMORY_SCOPE_AGENT) == POISON)
        __builtin_amdgcn_s_sleep(1);
    }
    __syncthreads();
    {
      #pragma unroll
      for (int i = 0; i < 2; i++) {
        const uint32_t* p = kp + (h0+i)*16 + zbL;
        uint32_t v = __hip_atomic_load(p, __ATOMIC_RELAXED, __HIP_MEMORY_SCOPE_AGENT);
        while (v == POISON) {
          __builtin_amdgcn_s_sleep(1);
          v = __hip_atomic_load(p, __ATOMIC_RELAXED, __HIP_MEMORY_SCOPE_AGENT);
        }
        z[i] += dt6*(zacc[i] + __uint_as_float(v));
      }
    }
    float o0 = z[0]*outw[h0] + z[1]*outw[h0+1];
    float o1 = z[0]*outw[64+h0] + z[1]*outw[64+h0+1];
    __syncthreads();
    dxs[hg*32 + zbL*2 + 0] = o0;    // po[32 grp][16 b][2]
    dxs[hg*32 + zbL*2 + 1] = o1;
    __syncthreads();
    if (tid < 32) {
      int bloc = tid >> 1, comp = tid & 1;
      float s = outb[comp];
      #pragma unroll
      for (int g = 0; g < 32; g++) s += dxs[g*32 + bloc*2 + comp];
      int b = B0 + bloc;
      if (*flag) ((unsigned short*)dout)[b*2 + comp] = f2bf(s);
      else       ((float*)dout)[b*2 + comp] = s;
    }
  }
}

// ---------------- host ----------------
extern "C" void kernel_launch(void* const* d_in, const int* in_sizes, int n_in,
                              void* d_out, int out_size, void* d_ws, size_t ws_size,
                              hipStream_t stream) {
  (void)in_sizes; (void)n_in; (void)out_size; (void)ws_size;
  float* ws = (float*)d_ws;
  size_t o = 0;
  auto alloc = [&](size_t n) { size_t r = o; o += (n + 63) & ~(size_t)63; return r; };
  size_t o_flag = alloc(64);
  size_t o_xf   = alloc(262144);
  size_t o_c1w  = alloc(800);
  size_t o_c1b  = alloc(32);
  size_t o_c2w  = alloc(9216);
  size_t o_c2b  = alloc(32);
  size_t o_a1w  = alloc(128);
  size_t o_a1b  = alloc(4);
  size_t o_a2w  = alloc(128);
  size_t o_a2b  = alloc(32);
  size_t o_iwT  = alloc(32768);
  size_t o_ib   = alloc(64);
  size_t o_f1b  = alloc(128);
  size_t o_f2b  = alloc(32768);
  size_t o_ow   = alloc(128);
  size_t o_ob   = alloc(2);
  size_t o_z0   = alloc(4096);
  size_t o_attm = alloc(2048);
  size_t o_atts = alloc(2048);
  size_t o_w1bf = alloc(4096);      // ushort[8192]
  size_t o_w2bf = alloc(2097152);   // ushort[4194304]
  size_t o_h1   = alloc(8388608);   // conv1 out; later pooled+seq
  size_t o_h2   = alloc(8388608);   // conv2 out; later dxt (253*32768 floats)
  size_t o_kpart= alloc(4128768);   // k data [504][4][64][16] — fresh, harness-poisoned
  size_t o_pool = o_h1;
  size_t o_seq  = o_h1 + 2097152;
  size_t o_dxt  = o_h2;

  int* flag = (int*)(ws + o_flag);

  hipLaunchKernelGGL(k_detect, dim3(1), dim3(256), 0, stream, (const uint32_t*)d_in[0], flag);

  CvtArgs ca;
  const int  si[NCVT]  = {0,1,2,3,4,5,6,7,8,9,10,12,14,15,16};
  const size_t dofs[NCVT] = {o_xf,o_c1w,o_c1b,o_c2w,o_c2b,o_a1w,o_a1b,o_a2w,o_a2b,o_iwT,o_ib,o_f1b,o_f2b,o_ow,o_ob};
  const int  ln[NCVT]  = {262144,800,32,9216,32,128,4,128,32,32768,64,128,32768,128,2};
  int tot = 0;
  for (int i = 0; i < NCVT; i++) {
    ca.src[i] = d_in[si[i]];
    ca.dstoff[i] = (int)dofs[i];
    ca.len[i] = ln[i];
    ca.kind[i] = (si[i] == 9) ? 1 : ((si[i] == 3) ? 2 : 0);
    tot += ln[i];
  }
  ca.total = tot;
  hipLaunchKernelGGL(k_convert, dim3(512), dim3(256), 0, stream, ca, ws, flag);
  hipLaunchKernelGGL(k_wbf16, dim3(2048), dim3(256), 0, stream, d_in[13], d_in[11],
                     (unsigned short*)(ws + o_w2bf), (unsigned short*)(ws + o_w1bf), flag);
  hipLaunchKernelGGL(k_conv1, dim3(32,64), dim3(128), 0, stream, ws+o_xf, ws+o_c1w, ws+o_c1b, ws+o_h1);
  hipLaunchKernelGGL(k_conv2, dim3(32,64), dim3(256), 0, stream, ws+o_h1, ws+o_c2w, ws+o_c2b, ws+o_h2);
  hipLaunchKernelGGL(k_pool, dim3(2048), dim3(256), 0, stream, ws+o_h2, ws+o_pool, ws+o_attm);
  hipLaunchKernelGGL(k_att, dim3(1), dim3(64), 0, stream, ws+o_attm, ws+o_a1w, ws+o_a1b, ws+o_a2w, ws+o_a2b, ws+o_atts);
  hipLaunchKernelGGL(k_seq, dim3(2048), dim3(256), 0, stream, ws+o_pool, ws+o_atts, ws+o_seq);
  hipLaunchKernelGGL(k_spline, dim3(128), dim3(256), 0, stream, ws+o_seq, ws+o_dxt);
  hipLaunchKernelGGL(k_z0, dim3(64), dim3(64), 0, stream, ws+o_seq, ws+o_iwT, ws+o_ib, ws+o_z0);

  hipLaunchKernelGGL(k_ode, dim3(256), dim3(512), 0, stream,
                     ws + o_z0,
                     (const unsigned short*)(ws + o_w2bf),
                     (const unsigned short*)(ws + o_w1bf),
                     ws + o_f1b, ws + o_f2b,
                     ws + o_dxt, ws + o_ow, ws + o_ob,
                     (uint32_t*)(ws + o_kpart),
                     d_out, (const int*)flag);
}

// Round 4
// 1433.942 us; speedup vs baseline: 1.9140x; 1.0587x over previous
//
#include <hip/hip_runtime.h>
#include <hip/hip_bf16.h>
#include <stdint.h>

#define NSTEP 126
#define NEVAL 504
#define POISON 0xAAAAAAAAu

typedef __bf16 v8bf __attribute__((ext_vector_type(8)));
typedef float  v4f  __attribute__((ext_vector_type(4)));

__device__ __forceinline__ unsigned short f2bf(float x) {
  union { float f; uint32_t u; } v; v.f = x;
  uint32_t u = v.u;
  uint32_t r = (u + 0x7FFFu + ((u >> 16) & 1u)) >> 16;
  return (unsigned short)r;
}
__device__ __forceinline__ float bf2f(unsigned short b) {
  union { uint32_t u; float f; } v; v.u = ((uint32_t)b) << 16;
  return v.f;
}
// packed RNE f32->bf16x2 (same rounding as f2bf; HW-validated rounds 1-3)
__device__ __forceinline__ uint32_t cvt_pk_bf16(float lo, float hi) {
  uint32_t r;
  asm("v_cvt_pk_bf16_f32 %0, %1, %2" : "=v"(r) : "v"(lo), "v"(hi));
  return r;
}

// raw barrier: LDS-visibility only (lgkmcnt), does NOT drain vmcnt —
// the k-store and global prefetches stay in flight across it
// (validated v8/v9 runs).
#define BARL() asm volatile("s_waitcnt lgkmcnt(0)\n\ts_barrier" ::: "memory")

// ---------------- dtype detection ----------------
__global__ void k_detect(const uint32_t* __restrict__ xw, int* flag) {
  __shared__ int cnt;
  if (threadIdx.x == 0) cnt = 0;
  __syncthreads();
  uint32_t w = xw[threadIdx.x];
  int e = (int)((w >> 7) & 0xFF);
  int good = ((e >= 100) && (e <= 144)) || ((w & 0xFFFFu) == 0u);
  atomicAdd(&cnt, good);
  __syncthreads();
  if (threadIdx.x == 0) *flag = (cnt >= 192) ? 1 : 0;
}

// ---------------- input conversion ----------------
#define NCVT 15
struct CvtArgs {
  const void* src[NCVT];
  int dstoff[NCVT];
  int len[NCVT];
  int kind[NCVT];   // 1 = transpose initial_w; 2 = conv2 weight relayout
  int total;
};
__global__ void k_convert(CvtArgs a, float* __restrict__ ws, const int* __restrict__ flag) {
  int f = *flag;
  for (int i = blockIdx.x*256 + threadIdx.x; i < a.total; i += gridDim.x*256) {
    int t = 0; int rem = i;
    while (rem >= a.len[t]) { rem -= a.len[t]; t++; }
    float v = f ? bf2f(((const unsigned short*)a.src[t])[rem])
                : ((const float*)a.src[t])[rem];
    int d;
    if (a.kind[t] == 1) { int h = rem >> 9, c = rem & 511; d = a.dstoff[t] + c*64 + h; }
    else if (a.kind[t] == 2) {
      int co = rem / 288, r2 = rem % 288;
      int ci = r2 / 9, tt = r2 % 9;
      d = a.dstoff[t] + (co >> 4)*4608 + (ci*16 + (co & 15))*9 + tt;
    }
    else d = a.dstoff[t] + rem;
    ws[d] = v;
  }
}

__global__ void k_wbf16(const void* __restrict__ w2src, const void* __restrict__ w1src,
                        unsigned short* __restrict__ w2bf, unsigned short* __restrict__ w1bf,
                        const int* __restrict__ flag) {
  int f = *flag;
  const long N2 = 4194304, N1 = 8192;
  for (long i = (long)blockIdx.x*256 + threadIdx.x; i < N2 + N1; i += (long)gridDim.x*256) {
    if (i < N2) w2bf[i] = f ? ((const unsigned short*)w2src)[i] : f2bf(((const float*)w2src)[i]);
    else { long j = i - N2; w1bf[j] = f ? ((const unsigned short*)w1src)[j] : f2bf(((const float*)w1src)[j]); }
  }
}

// ---------------- conv1 5x5 pad2, 1->32, relu ----------------
__global__ void k_conv1(const float* __restrict__ xf, const float* __restrict__ w,
                        const float* __restrict__ bias, float* __restrict__ h1) {
  int x = threadIdx.x;        // 0..127
  int y = blockIdx.x;         // 0..31
  int b = blockIdx.y;         // 0..63
  const float* xin = xf + (long)b*4096;
  float in[25];
  #pragma unroll
  for (int ky = 0; ky < 5; ky++) {
    int yy = y + ky - 2;
    #pragma unroll
    for (int kx = 0; kx < 5; kx++) {
      int xx = x + kx - 2;
      in[ky*5+kx] = (yy >= 0 && yy < 32 && xx >= 0 && xx < 128) ? xin[yy*128 + xx] : 0.f;
    }
  }
  for (int co = 0; co < 32; co++) {
    float acc = bias[co];
    #pragma unroll
    for (int t = 0; t < 25; t++) acc += in[t] * w[co*25 + t];
    h1[(((long)b*32 + co)*32 + y)*128 + x] = fmaxf(acc, 0.f);
  }
}

// ---------------- conv2 3x3 pad1, 32->32, relu ----------------
#define LD2 132
__global__ __launch_bounds__(256) void k_conv2(const float* __restrict__ h1, const float* __restrict__ w,
                                               const float* __restrict__ bias, float* __restrict__ h2) {
  __shared__ float s[32][3][LD2];
  int y = blockIdx.x, b = blockIdx.y;
  int tid = threadIdx.x;
  for (int i = tid; i < 32*3*LD2; i += 256) {
    int ci = i / (3*LD2);
    int r  = (i / LD2) % 3;
    int xx = i % LD2;
    int yy = y + r - 1, sx = xx - 1;
    float v = 0.f;
    if (yy >= 0 && yy < 32 && sx >= 0 && sx < 128) v = h1[(((long)b*32+ci)*32+yy)*128+sx];
    s[ci][r][xx] = v;
  }
  __syncthreads();
  int x = tid & 127;
  int half = __builtin_amdgcn_readfirstlane(tid >> 7);
  const float* wb = w + half*4608;          // [ci][co16][9] contiguous
  float acc[16];
  #pragma unroll
  for (int i = 0; i < 16; i++) acc[i] = bias[half*16 + i];
  #pragma unroll 2
  for (int ci = 0; ci < 32; ci++) {
    float xv[9];
    #pragma unroll
    for (int r = 0; r < 3; r++)
      #pragma unroll
      for (int k = 0; k < 3; k++) xv[r*3+k] = s[ci][r][x + k];
    #pragma unroll
    for (int co = 0; co < 16; co++) {
      const float* wr = wb + (ci*16 + co)*9;
      #pragma unroll
      for (int t = 0; t < 9; t++) acc[co] += xv[t] * wr[t];
    }
  }
  #pragma unroll
  for (int co = 0; co < 16; co++)
    h2[(((long)b*32 + half*16 + co)*32 + y)*128 + x] = fmaxf(acc[co], 0.f);
}

// ---------------- maxpool 2x2 + channel mean ----------------
__global__ void k_pool(const float* __restrict__ h2, float* __restrict__ pooled, float* __restrict__ attm) {
  int bc = blockIdx.x;                 // b*32+c
  const float* src = h2 + (long)bc*4096;
  float* dst = pooled + (long)bc*1024;
  float sum = 0.f;
  for (int i = threadIdx.x; i < 1024; i += 256) {
    int py = i >> 6, px = i & 63;
    const float* p = src + py*256 + px*2;
    float m = fmaxf(fmaxf(p[0], p[1]), fmaxf(p[128], p[129]));
    dst[i] = m;
    sum += m;
  }
  __shared__ float red[256];
  red[threadIdx.x] = sum;
  __syncthreads();
  for (int s2 = 128; s2 > 0; s2 >>= 1) {
    if (threadIdx.x < s2) red[threadIdx.x] += red[threadIdx.x + s2];
    __syncthreads();
  }
  if (threadIdx.x == 0) attm[bc] = red[0] * (1.f/1024.f);
}

// ---------------- attention MLP ----------------
__global__ void k_att(const float* __restrict__ attm, const float* __restrict__ w1, const float* __restrict__ b1,
                      const float* __restrict__ w2, const float* __restrict__ b2, float* __restrict__ atts) {
  int b = threadIdx.x;
  if (b < 64) {
    float hb[4];
    #pragma unroll
    for (int j = 0; j < 4; j++) {
      float s = b1[j];
      for (int i = 0; i < 32; i++) s += attm[b*32+i]*w1[j*32+i];
      hb[j] = fmaxf(s, 0.f);
    }
    for (int o = 0; o < 32; o++) {
      float s = b2[o];
      #pragma unroll
      for (int j = 0; j < 4; j++) s += hb[j]*w2[o*4+j];
      atts[b*32+o] = 1.f/(1.f + __expf(-s));
    }
  }
}

// ---------------- scale + transpose to seq[b][t][f], f=c*16+hh ----------------
__global__ void k_seq(const float* __restrict__ pooled, const float* __restrict__ atts, float* __restrict__ seq) {
  for (int idx = blockIdx.x*256 + threadIdx.x; idx < 64*64*512; idx += gridDim.x*256) {
    int b = idx >> 15;
    int t = (idx >> 9) & 63;
    int fch = idx & 511;
    int c = fch >> 4, hh = fch & 15;
    seq[idx] = pooled[(((long)b*32 + c)*16 + hh)*64 + t] * atts[b*32 + c];
  }
}

// ---------------- natural cubic spline coeffs + dXdt table (fused) ----------------
__global__ __launch_bounds__(256, 1) void k_spline(const float* __restrict__ seq,
                                                   float* __restrict__ dxt) {
  int id = blockIdx.x*256 + threadIdx.x;     // 0..32767
  int b = id >> 9, f = id & 511;
  const float* xp = seq + (long)b*32768 + f;
  float xv[64];
  #pragma unroll
  for (int t = 0; t < 64; t++) xv[t] = xp[t*512];
  float cp[62], dp[62];
  float pc = 0.f, pd = 0.f;
  #pragma unroll
  for (int i = 0; i < 62; i++) {
    float rhs = 6.f*(xv[i+2] - 2.f*xv[i+1] + xv[i]);
    float inv = 1.f/(4.f - pc);
    pc = inv;
    pd = (rhs - pd)*inv;
    cp[i] = pc; dp[i] = pd;
  }
  #pragma unroll
  for (int i = 60; i >= 0; i--) dp[i] = dp[i] - cp[i]*dp[i+1];
  const float i6 = 1.f/6.f;
  float* op = dxt + (long)b*512 + f;
  #pragma unroll
  for (int t = 0; t < 63; t++) {
    float M0 = (t == 0)  ? 0.f : dp[t-1];
    float M1 = (t == 62) ? 0.f : dp[t];
    float sb = (xv[t+1] - xv[t]) - (2.f*M0 + M1)*i6;
    float sc = 0.5f*M0;
    float sd = (M1 - M0)*i6;
    float* o = op + (long)(4*t)*32768;
    o[0]      = sb;                                  // fr = 0
    o[32768]  = sb + 0.5f*sc + 0.1875f*sd;           // fr = 0.25
    o[65536]  = sb + sc + 0.75f*sd;                  // fr = 0.5
    o[98304]  = sb + 1.5f*sc + 1.6875f*sd;           // fr = 0.75
    if (t == 62) o[131072] = sb + 2.f*sc + 3.f*sd;   // m = 252, fr = 1
  }
}

// ---------------- z0 = seq[:,0,:] @ initial_w^T + b ----------------
__global__ void k_z0(const float* __restrict__ seq, const float* __restrict__ iwT,
                     const float* __restrict__ ib, float* __restrict__ z0) {
  __shared__ float s0[512];
  int b = blockIdx.x, h = threadIdx.x;
  for (int c = h; c < 512; c += 64) s0[c] = seq[(long)b*32768 + c];
  __syncthreads();
  float acc = ib[h];
  for (int c = 0; c < 512; c++) acc += s0[c]*iwT[c*64 + h];
  z0[b*64 + h] = acc;
}

// ---------------- persistent RK4 CDE integrator ----------------
// v10 = v9 minus the dedicated poll wave + poll barrier. Every thread spins
// directly on its OWN two kv words (discovery and data-delivery are the same
// load), merging the previous two serial LLC round trips (poll RT -> barrier
// -> kv RT) into one RT + short retry. First check lands at the same wall
// time v9's first poll landed (~50% visible), so retries are 1-2 with
// s_sleep — unlike v8's always-poison lockstep prefetch.
// WAR audit with 3 barriers/eval (poll barrier deleted):
//   zs-write(e) vs W1 zs-read(e-1): BARL3+BARL4 between.  dxs-write(e) vs
//   W2 dxs-read(e-1): BARL4 between (lgkmcnt(0) retires reads).  ub, kred:
//   >=2 barriers. Producer store remains the readiness signal.
__global__ __launch_bounds__(512, 2) void k_ode(
    const float* __restrict__ z0buf,
    const unsigned short* __restrict__ w2bf,   // [32768][128]
    const unsigned short* __restrict__ w1bf,   // [128][64]
    const float* __restrict__ f1bias,
    const float* __restrict__ f2bias,
    const float* __restrict__ dxt,             // [253][64][512]
    const float* __restrict__ outw,
    const float* __restrict__ outb,
    uint32_t* kpart,                           // [504][4 bq][64 hb][16 b] (poisoned)
    void* dout,
    const int* __restrict__ flag)
{
  __shared__ __align__(16) unsigned short zs[16*72];       // z bf16 [16 b][64 h] pad
  __shared__ __align__(16) unsigned short ub[16*136];      // u bf16 [16 b][128 u] pad
  __shared__ __align__(16) float dxs[16*524 + 10560];      // dx fp32 + CU-exclusivity pad
  __shared__ float kred[128];                              // [16 b][8 wv]

  int tid = threadIdx.x;
  int bl  = blockIdx.x;
  int hb  = bl >> 2;            // 0..63 — this block's h (all 512 c)
  int bq  = bl & 3;             // b-quarter
  int B0  = bq*16;
  int lane = tid & 63, wv = tid >> 6;   // 8 waves
  int q = lane >> 4, ln = lane & 15;

  // ---- persistent fragments: wave wv owns c-rows wv*64..+64 ----
  v8bf w2f[4][4];
  #pragma unroll
  for (int jt = 0; jt < 4; jt++)
    #pragma unroll
    for (int ks = 0; ks < 4; ks++) {
      long row = (long)hb*512 + wv*64 + jt*16 + ln;
      w2f[jt][ks] = *(const v8bf*)(w2bf + row*128 + ks*32 + q*8);
    }
  v8bf w1f[2];                  // u-rows wv*16..+16
  #pragma unroll
  for (int ks = 0; ks < 2; ks++)
    w1f[ks] = *(const v8bf*)(w1bf + (wv*16 + ln)*64 + ks*32 + q*8);
  float fb2[4][4];
  #pragma unroll
  for (int jt = 0; jt < 4; jt++)
    #pragma unroll
    for (int r = 0; r < 4; r++)
      fb2[jt][r] = f2bias[(long)hb*512 + wv*64 + jt*16 + q*4 + r];
  float fb1[4];
  #pragma unroll
  for (int r = 0; r < 4; r++)
    fb1[r] = f1bias[wv*16 + q*4 + r];

  // z state: thread owns b-local = tid&15, h-pair = (tid>>4)*2
  int zbL = tid & 15;
  int hg  = tid >> 4;           // 0..31
  int h0  = hg*2;               // 0..62
  float z[2], zacc[2];
  #pragma unroll
  for (int i = 0; i < 2; i++) { z[i] = z0buf[(B0+zbL)*64 + h0 + i]; zacc[i] = 0.f; }

  const float dt6 = 0.5f/6.f;
  int e = 0;
  for (int step = 0; step < NSTEP; step++) {
    #pragma unroll 1
    for (int stage = 0; stage < 4; stage++, e++) {
      bool do_dx = (stage == 1) || (stage == 3) || (e == 0);
      int m = 2*step + ((stage + 1) >> 1);
      float4 dxr[4];
      // dxr loads issued FIRST (older in vmcnt order) so the dxs-write wait
      // below does not force the younger kv loads to retire.
      if (do_dx) {
        #pragma unroll
        for (int i = 0; i < 4; i++) {
          int fi = i*512 + tid;          // 2048 float4 = [16 b][128 f4]
          int bb = fi >> 7, c4 = fi & 127;
          dxr[i] = *(const float4*)(dxt + (long)m*32768 + (B0+bb)*512 + c4*4);
        }
      }
      if (e > 0) {
        const uint32_t* kp = kpart + ((long)(e-1)*4 + bq)*1024;
        // direct per-thread kv loads: discovery == delivery (one LLC RT)
        uint32_t kvu[2];
        const uint32_t* p0 = kp + (h0+0)*16 + zbL;
        const uint32_t* p1 = kp + (h0+1)*16 + zbL;
        kvu[0] = __hip_atomic_load(p0, __ATOMIC_RELAXED, __HIP_MEMORY_SCOPE_AGENT);
        kvu[1] = __hip_atomic_load(p1, __ATOMIC_RELAXED, __HIP_MEMORY_SCOPE_AGENT);
        // dxs LDS writes overlap the kv load latency
        if (do_dx) {
          #pragma unroll
          for (int i = 0; i < 4; i++) {
            int fi = i*512 + tid;
            int bb = fi >> 7, c4 = fi & 127;
            *(float4*)(dxs + bb*524 + c4*4) = dxr[i];
          }
        }
        while (kvu[0] == POISON) {
          __builtin_amdgcn_s_sleep(1);
          kvu[0] = __hip_atomic_load(p0, __ATOMIC_RELAXED, __HIP_MEMORY_SCOPE_AGENT);
        }
        while (kvu[1] == POISON) {
          __builtin_amdgcn_s_sleep(1);
          kvu[1] = __hip_atomic_load(p1, __ATOMIC_RELAXED, __HIP_MEMORY_SCOPE_AGENT);
        }
        float kv0 = __uint_as_float(kvu[0]);
        float kv1 = __uint_as_float(kvu[1]);
        if (stage == 0) {
          z[0] += dt6*(zacc[0] + kv0);
          z[1] += dt6*(zacc[1] + kv1);
          zacc[0] = 0.f; zacc[1] = 0.f;
          *(uint32_t*)(zs + zbL*72 + h0) = cvt_pk_bf16(z[0], z[1]);
        } else {
          float wk = (stage == 1) ? 1.f : 2.f;
          float aa = (stage == 3) ? 0.5f : 0.25f;
          zacc[0] += wk*kv0;
          zacc[1] += wk*kv1;
          *(uint32_t*)(zs + zbL*72 + h0) = cvt_pk_bf16(z[0] + aa*kv0, z[1] + aa*kv1);
        }
      } else {
        *(uint32_t*)(zs + zbL*72 + h0) = cvt_pk_bf16(z[0], z[1]);
        if (do_dx) {
          #pragma unroll
          for (int i = 0; i < 4; i++) {
            int fi = i*512 + tid;
            int bb = fi >> 7, c4 = fi & 127;
            *(float4*)(dxs + bb*524 + c4*4) = dxr[i];
          }
        }
      }
      BARL();
      // W1: wave computes u rows wv*16..+16 for the 16 b (bias in C-in)
      v8bf zf[2];
      #pragma unroll
      for (int ks = 0; ks < 2; ks++)
        zf[ks] = *(const v8bf*)(zs + ln*72 + ks*32 + q*8);
      {
        v4f ua = (v4f){fb1[0], fb1[1], fb1[2], fb1[3]};
        #pragma unroll
        for (int ks = 0; ks < 2; ks++)
          ua = __builtin_amdgcn_mfma_f32_16x16x32_bf16(w1f[ks], zf[ks], ua, 0, 0, 0);
        uint2 upk;
        upk.x = cvt_pk_bf16(fmaxf(ua[0], 0.f), fmaxf(ua[1], 0.f));
        upk.y = cvt_pk_bf16(fmaxf(ua[2], 0.f), fmaxf(ua[3], 0.f));
        *(uint2*)(ub + ln*136 + wv*16 + q*4) = upk;
      }
      BARL();
      // W2 (wave's 64 c-rows, all 16 b) + tanh + dot dx -> per-wave partial
      v8bf uf[4];
      #pragma unroll
      for (int ks = 0; ks < 4; ks++)
        uf[ks] = *(const v8bf*)(ub + ln*136 + ks*32 + q*8);
      float ksum = 0.f;
      #pragma unroll
      for (int jt = 0; jt < 4; jt++) {
        v4f acc = (v4f){fb2[jt][0], fb2[jt][1], fb2[jt][2], fb2[jt][3]};
        #pragma unroll
        for (int ks = 0; ks < 4; ks++)
          acc = __builtin_amdgcn_mfma_f32_16x16x32_bf16(w2f[jt][ks], uf[ks], acc, 0, 0, 0);
        v4f dx4 = *(const v4f*)(dxs + ln*524 + wv*64 + jt*16 + q*4);
        #pragma unroll
        for (int r = 0; r < 4; r++) {
          float xv2 = acc[r];
          float ex = __expf(2.f*xv2);
          float th = 1.f - 2.f*__builtin_amdgcn_rcpf(ex + 1.f);
          ksum += th*dx4[r];
        }
      }
      ksum += __shfl_xor(ksum, 16, 64);
      ksum += __shfl_xor(ksum, 32, 64);
      if (lane < 16)
        kred[ln*8 + wv] = ksum;
      BARL();
      // wave0: combine 8 wave-partials (contiguous b128 reads) -> FINAL k,
      // one 64B line store. The store itself is the readiness signal.
      if (tid < 16) {
        const float* kr = kred + tid*8;
        float v = ((((((kr[0]+kr[1])+kr[2])+kr[3])+kr[4])+kr[5])+kr[6])+kr[7];
        uint32_t uv = __float_as_uint(v);
        if (uv == POISON) uv ^= 1u;
        __hip_atomic_store(kpart + (((long)e*4 + bq)*64 + hb)*16 + tid, uv,
                           __ATOMIC_RELAXED, __HIP_MEMORY_SCOPE_AGENT);
      }
      // no trailing barrier: BARL4(e) + BARL2(e+1) cover all WAR hazards
    }
  }
  // final: only output blocks (hb==0 -> bl<4) need the last k
  if (hb == 0) {
    const uint32_t* kp = kpart + ((long)(NEVAL-1)*4 + bq)*1024;
    {
      #pragma unroll
      for (int i = 0; i < 2; i++) {
        const uint32_t* p = kp + (h0+i)*16 + zbL;
        uint32_t v = __hip_atomic_load(p, __ATOMIC_RELAXED, __HIP_MEMORY_SCOPE_AGENT);
        while (v == POISON) {
          __builtin_amdgcn_s_sleep(1);
          v = __hip_atomic_load(p, __ATOMIC_RELAXED, __HIP_MEMORY_SCOPE_AGENT);
        }
        z[i] += dt6*(zacc[i] + __uint_as_float(v));
      }
    }
    float o0 = z[0]*outw[h0] + z[1]*outw[h0+1];
    float o1 = z[0]*outw[64+h0] + z[1]*outw[64+h0+1];
    __syncthreads();
    dxs[hg*32 + zbL*2 + 0] = o0;    // po[32 grp][16 b][2]
    dxs[hg*32 + zbL*2 + 1] = o1;
    __syncthreads();
    if (tid < 32) {
      int bloc = tid >> 1, comp = tid & 1;
      float s = outb[comp];
      #pragma unroll
      for (int g = 0; g < 32; g++) s += dxs[g*32 + bloc*2 + comp];
      int b = B0 + bloc;
      if (*flag) ((unsigned short*)dout)[b*2 + comp] = f2bf(s);
      else       ((float*)dout)[b*2 + comp] = s;
    }
  }
}

// ---------------- host ----------------
extern "C" void kernel_launch(void* const* d_in, const int* in_sizes, int n_in,
                              void* d_out, int out_size, void* d_ws, size_t ws_size,
                              hipStream_t stream) {
  (void)in_sizes; (void)n_in; (void)out_size; (void)ws_size;
  float* ws = (float*)d_ws;
  size_t o = 0;
  auto alloc = [&](size_t n) { size_t r = o; o += (n + 63) & ~(size_t)63; return r; };
  size_t o_flag = alloc(64);
  size_t o_xf   = alloc(262144);
  size_t o_c1w  = alloc(800);
  size_t o_c1b  = alloc(32);
  size_t o_c2w  = alloc(9216);
  size_t o_c2b  = alloc(32);
  size_t o_a1w  = alloc(128);
  size_t o_a1b  = alloc(4);
  size_t o_a2w  = alloc(128);
  size_t o_a2b  = alloc(32);
  size_t o_iwT  = alloc(32768);
  size_t o_ib   = alloc(64);
  size_t o_f1b  = alloc(128);
  size_t o_f2b  = alloc(32768);
  size_t o_ow   = alloc(128);
  size_t o_ob   = alloc(2);
  size_t o_z0   = alloc(4096);
  size_t o_attm = alloc(2048);
  size_t o_atts = alloc(2048);
  size_t o_w1bf = alloc(4096);      // ushort[8192]
  size_t o_w2bf = alloc(2097152);   // ushort[4194304]
  size_t o_h1   = alloc(8388608);   // conv1 out; later pooled+seq
  size_t o_h2   = alloc(8388608);   // conv2 out; later dxt (253*32768 floats)
  size_t o_kpart= alloc(4128768);   // k data [504][4][64][16] — fresh, harness-poisoned
  size_t o_pool = o_h1;
  size_t o_seq  = o_h1 + 2097152;
  size_t o_dxt  = o_h2;

  int* flag = (int*)(ws + o_flag);

  hipLaunchKernelGGL(k_detect, dim3(1), dim3(256), 0, stream, (const uint32_t*)d_in[0], flag);

  CvtArgs ca;
  const int  si[NCVT]  = {0,1,2,3,4,5,6,7,8,9,10,12,14,15,16};
  const size_t dofs[NCVT] = {o_xf,o_c1w,o_c1b,o_c2w,o_c2b,o_a1w,o_a1b,o_a2w,o_a2b,o_iwT,o_ib,o_f1b,o_f2b,o_ow,o_ob};
  const int  ln[NCVT]  = {262144,800,32,9216,32,128,4,128,32,32768,64,128,32768,128,2};
  int tot = 0;
  for (int i = 0; i < NCVT; i++) {
    ca.src[i] = d_in[si[i]];
    ca.dstoff[i] = (int)dofs[i];
    ca.len[i] = ln[i];
    ca.kind[i] = (si[i] == 9) ? 1 : ((si[i] == 3) ? 2 : 0);
    tot += ln[i];
  }
  ca.total = tot;
  hipLaunchKernelGGL(k_convert, dim3(512), dim3(256), 0, stream, ca, ws, flag);
  hipLaunchKernelGGL(k_wbf16, dim3(2048), dim3(256), 0, stream, d_in[13], d_in[11],
                     (unsigned short*)(ws + o_w2bf), (unsigned short*)(ws + o_w1bf), flag);
  hipLaunchKernelGGL(k_conv1, dim3(32,64), dim3(128), 0, stream, ws+o_xf, ws+o_c1w, ws+o_c1b, ws+o_h1);
  hipLaunchKernelGGL(k_conv2, dim3(32,64), dim3(256), 0, stream, ws+o_h1, ws+o_c2w, ws+o_c2b, ws+o_h2);
  hipLaunchKernelGGL(k_pool, dim3(2048), dim3(256), 0, stream, ws+o_h2, ws+o_pool, ws+o_attm);
  hipLaunchKernelGGL(k_att, dim3(1), dim3(64), 0, stream, ws+o_attm, ws+o_a1w, ws+o_a1b, ws+o_a2w, ws+o_a2b, ws+o_atts);
  hipLaunchKernelGGL(k_seq, dim3(2048), dim3(256), 0, stream, ws+o_pool, ws+o_atts, ws+o_seq);
  hipLaunchKernelGGL(k_spline, dim3(128), dim3(256), 0, stream, ws+o_seq, ws+o_dxt);
  hipLaunchKernelGGL(k_z0, dim3(64), dim3(64), 0, stream, ws+o_seq, ws+o_iwT, ws+o_ib, ws+o_z0);

  hipLaunchKernelGGL(k_ode, dim3(256), dim3(512), 0, stream,
                     ws + o_z0,
                     (const unsigned short*)(ws + o_w2bf),
                     (const unsigned short*)(ws + o_w1bf),
                     ws + o_f1b, ws + o_f2b,
                     ws + o_dxt, ws + o_ow, ws + o_ob,
                     (uint32_t*)(ws + o_kpart),
                     d_out, (const int*)flag);
}